// Round 2
// baseline (3249.410 us; speedup 1.0000x reference)
//
#include <hip/hip_runtime.h>
#include <cstddef>

#define B_ 64
#define T_ 512
#define C_ 384
#define H_ 6
#define HD_ 64
#define FF_ 1536

// ---------------------------------------------------------------------------
// Generic fp32 GEMM: A[M][K] row-major, Bm[K][N] row-major (ldb == N == out ld)
// MODE 0: out = acc + bias[n] + res[row][n]
// MODE 1: out = relu(acc + bias[n])
// tile 64x64, BK=16, 256 threads, 4x4 per thread
// ---------------------------------------------------------------------------
template<int MODE>
__global__ __launch_bounds__(256)
void gemm_ep(const float* __restrict__ A, const float* __restrict__ Bm,
             const float* __restrict__ bias, const float* __restrict__ res,
             float* __restrict__ out, int K, int ldb)
{
    __shared__ float As[16][68];
    __shared__ float Bs[16][68];
    const int m0 = blockIdx.x * 64;
    const int n0 = blockIdx.y * 64;
    const int tid = threadIdx.x;
    const int tr = tid >> 4, tc = tid & 15;
    const int ra = tid >> 2, ka = (tid & 3) * 4;   // A-tile load coords
    const int kb = tid >> 4, nb = (tid & 15) * 4;  // B-tile load coords

    float acc[4][4] = {};

    for (int k0 = 0; k0 < K; k0 += 16) {
        __syncthreads();
        float4 av = *reinterpret_cast<const float4*>(&A[(size_t)(m0 + ra) * K + k0 + ka]);
        As[ka + 0][ra] = av.x; As[ka + 1][ra] = av.y;
        As[ka + 2][ra] = av.z; As[ka + 3][ra] = av.w;
        float4 bv = *reinterpret_cast<const float4*>(&Bm[(size_t)(k0 + kb) * ldb + n0 + nb]);
        *reinterpret_cast<float4*>(&Bs[kb][nb]) = bv;
        __syncthreads();
        #pragma unroll
        for (int kk = 0; kk < 16; ++kk) {
            float4 a4 = *reinterpret_cast<const float4*>(&As[kk][tr * 4]);
            float4 b4 = *reinterpret_cast<const float4*>(&Bs[kk][tc * 4]);
            float a[4] = {a4.x, a4.y, a4.z, a4.w};
            float b[4] = {b4.x, b4.y, b4.z, b4.w};
            #pragma unroll
            for (int i = 0; i < 4; ++i)
                #pragma unroll
                for (int j = 0; j < 4; ++j)
                    acc[i][j] = fmaf(a[i], b[j], acc[i][j]);
        }
    }

    const int row0 = m0 + tr * 4;
    const int col0 = n0 + tc * 4;
    #pragma unroll
    for (int i = 0; i < 4; ++i) {
        const size_t o = (size_t)(row0 + i) * ldb + col0;
        #pragma unroll
        for (int j = 0; j < 4; ++j) {
            float v = acc[i][j] + bias[col0 + j];
            if (MODE == 0) v += res[o + j];
            if (MODE == 1) v = fmaxf(v, 0.0f);
            out[o + j] = v;
        }
    }
}

// ---------------------------------------------------------------------------
// QKV projection + bias + RoPE (on q,k). One block = 64 rows x one head of one
// of {q,k,v}.  X[M][C], W[h][C][HD] per head.  Out [CB,H,T,HD] (chunk-local).
// ---------------------------------------------------------------------------
__global__ __launch_bounds__(256)
void gemm_qkv(const float* __restrict__ X,
              const float* __restrict__ qw, const float* __restrict__ qb,
              const float* __restrict__ kw, const float* __restrict__ kb_,
              const float* __restrict__ vw, const float* __restrict__ vb,
              float* __restrict__ qo, float* __restrict__ ko, float* __restrict__ vo)
{
    const int which = blockIdx.y / H_;   // 0=q 1=k 2=v
    const int h     = blockIdx.y % H_;
    const float* W  = (which == 0 ? qw : which == 1 ? kw : vw) + (size_t)h * C_ * HD_;
    const float* bb = (which == 0 ? qb : which == 1 ? kb_ : vb) + h * HD_;
    float* outp     = (which == 0 ? qo : which == 1 ? ko : vo);

    __shared__ float As[16][68];
    __shared__ float Bs[16][68];
    const int m0 = blockIdx.x * 64;
    const int tid = threadIdx.x;
    const int tr = tid >> 4, tc = tid & 15;
    const int ra = tid >> 2, ka = (tid & 3) * 4;
    const int kb2 = tid >> 4, nb = (tid & 15) * 4;

    float acc[4][4] = {};

    for (int k0 = 0; k0 < C_; k0 += 16) {
        __syncthreads();
        float4 av = *reinterpret_cast<const float4*>(&X[(size_t)(m0 + ra) * C_ + k0 + ka]);
        As[ka + 0][ra] = av.x; As[ka + 1][ra] = av.y;
        As[ka + 2][ra] = av.z; As[ka + 3][ra] = av.w;
        float4 bv = *reinterpret_cast<const float4*>(&W[(size_t)(k0 + kb2) * HD_ + nb]);
        *reinterpret_cast<float4*>(&Bs[kb2][nb]) = bv;
        __syncthreads();
        #pragma unroll
        for (int kk = 0; kk < 16; ++kk) {
            float4 a4 = *reinterpret_cast<const float4*>(&As[kk][tr * 4]);
            float4 b4 = *reinterpret_cast<const float4*>(&Bs[kk][tc * 4]);
            float a[4] = {a4.x, a4.y, a4.z, a4.w};
            float b[4] = {b4.x, b4.y, b4.z, b4.w};
            #pragma unroll
            for (int i = 0; i < 4; ++i)
                #pragma unroll
                for (int j = 0; j < 4; ++j)
                    acc[i][j] = fmaf(a[i], b[j], acc[i][j]);
        }
    }

    const int d0 = tc * 4;
    #pragma unroll
    for (int i = 0; i < 4; ++i) {
        const int row = m0 + tr * 4 + i;
        const int b   = row >> 9;        // /T_  (chunk-local batch)
        const int t   = row & 511;       // %T_
        float v0 = acc[i][0] + bb[d0 + 0];
        float v1 = acc[i][1] + bb[d0 + 1];
        float v2 = acc[i][2] + bb[d0 + 2];
        float v3 = acc[i][3] + bb[d0 + 3];
        if (which < 2) {  // RoPE: rotate each even/odd pair by angle t (radians)
            float cs = cosf((float)t), sn = sinf((float)t);
            float r0 = cs * v0 - sn * v1, i0 = sn * v0 + cs * v1;
            float r1 = cs * v2 - sn * v3, i1 = sn * v2 + cs * v3;
            v0 = r0; v1 = i0; v2 = r1; v3 = i1;
        }
        const size_t o = (((size_t)(b * H_ + h)) * T_ + t) * HD_ + d0;
        outp[o + 0] = v0; outp[o + 1] = v1; outp[o + 2] = v2; outp[o + 3] = v3;
    }
}

// ---------------------------------------------------------------------------
// Flash-style causal attention, fp32.  One block = one (b,h) x 64 q-rows.
// scale = C^(-1/2) per reference.  Output written as [b,t, h*HD+d].
// ---------------------------------------------------------------------------
__global__ __launch_bounds__(256)
void attn_kernel(const float* __restrict__ Q, const float* __restrict__ K,
                 const float* __restrict__ V, float* __restrict__ out)
{
    const int qt = blockIdx.x, h = blockIdx.y, b = blockIdx.z;
    const int tid = threadIdx.x;
    const int tq = tid >> 4, tk = tid & 15;

    __shared__ float Qs[64][65];
    __shared__ float KPs[64][65];   // K tile, then reused for P tile
    __shared__ float Vs[64][65];

    const size_t base = ((size_t)(b * H_ + h)) * T_ * HD_;
    const int q0 = qt * 64;
    const float scale = 0.05103103630798288f;  // 384^-0.5

    for (int idx = tid; idx < 64 * 16; idx += 256) {
        int r = idx >> 4, seg = (idx & 15) * 4;
        float4 v4 = *reinterpret_cast<const float4*>(&Q[base + (size_t)(q0 + r) * HD_ + seg]);
        Qs[r][seg] = v4.x; Qs[r][seg + 1] = v4.y; Qs[r][seg + 2] = v4.z; Qs[r][seg + 3] = v4.w;
    }

    float m_[4], l_[4], O[4][4];
    #pragma unroll
    for (int i = 0; i < 4; ++i) {
        m_[i] = -INFINITY; l_[i] = 0.0f;
        #pragma unroll
        for (int j = 0; j < 4; ++j) O[i][j] = 0.0f;
    }

    for (int kt = 0; kt <= qt; ++kt) {
        const int k0 = kt * 64;
        __syncthreads();   // protect KPs/Vs from previous iteration's readers
        for (int idx = tid; idx < 64 * 16; idx += 256) {
            int r = idx >> 4, seg = (idx & 15) * 4;
            float4 kv = *reinterpret_cast<const float4*>(&K[base + (size_t)(k0 + r) * HD_ + seg]);
            KPs[r][seg] = kv.x; KPs[r][seg + 1] = kv.y; KPs[r][seg + 2] = kv.z; KPs[r][seg + 3] = kv.w;
            float4 vv = *reinterpret_cast<const float4*>(&V[base + (size_t)(k0 + r) * HD_ + seg]);
            Vs[r][seg] = vv.x; Vs[r][seg + 1] = vv.y; Vs[r][seg + 2] = vv.z; Vs[r][seg + 3] = vv.w;
        }
        __syncthreads();

        // S = Q K^T
        float s[4][4] = {};
        #pragma unroll 4
        for (int d = 0; d < 64; ++d) {
            float a_[4], b_[4];
            #pragma unroll
            for (int i = 0; i < 4; ++i) a_[i] = Qs[tq * 4 + i][d];
            #pragma unroll
            for (int j = 0; j < 4; ++j) b_[j] = KPs[tk * 4 + j][d];
            #pragma unroll
            for (int i = 0; i < 4; ++i)
                #pragma unroll
                for (int j = 0; j < 4; ++j)
                    s[i][j] = fmaf(a_[i], b_[j], s[i][j]);
        }

        const bool diag = (kt == qt);
        #pragma unroll
        for (int i = 0; i < 4; ++i)
            #pragma unroll
            for (int j = 0; j < 4; ++j) {
                float sv = s[i][j] * scale;
                if (diag && (k0 + tk * 4 + j > q0 + tq * 4 + i)) sv = -INFINITY;
                s[i][j] = sv;
            }

        // online softmax update (rows are shared by 16 lanes with same tq)
        float rmax[4];
        #pragma unroll
        for (int i = 0; i < 4; ++i)
            rmax[i] = fmaxf(fmaxf(s[i][0], s[i][1]), fmaxf(s[i][2], s[i][3]));
        #pragma unroll
        for (int off = 1; off < 16; off <<= 1)
            #pragma unroll
            for (int i = 0; i < 4; ++i)
                rmax[i] = fmaxf(rmax[i], __shfl_xor(rmax[i], off, 16));

        float corr[4], rsum[4];
        #pragma unroll
        for (int i = 0; i < 4; ++i) {
            float mn = fmaxf(m_[i], rmax[i]);
            corr[i] = __expf(m_[i] - mn);
            m_[i] = mn;
        }
        #pragma unroll
        for (int i = 0; i < 4; ++i) {
            float su = 0.0f;
            #pragma unroll
            for (int j = 0; j < 4; ++j) {
                float p = __expf(s[i][j] - m_[i]);
                s[i][j] = p; su += p;
            }
            rsum[i] = su;
        }
        #pragma unroll
        for (int off = 1; off < 16; off <<= 1)
            #pragma unroll
            for (int i = 0; i < 4; ++i)
                rsum[i] += __shfl_xor(rsum[i], off, 16);
        #pragma unroll
        for (int i = 0; i < 4; ++i) l_[i] = l_[i] * corr[i] + rsum[i];

        __syncthreads();   // everyone done reading KPs as K
        #pragma unroll
        for (int i = 0; i < 4; ++i)
            #pragma unroll
            for (int j = 0; j < 4; ++j) {
                KPs[tq * 4 + i][tk * 4 + j] = s[i][j];
                O[i][j] *= corr[i];
            }
        __syncthreads();   // P tile visible

        // O += P V
        #pragma unroll 4
        for (int kk = 0; kk < 64; ++kk) {
            float p_[4], v_[4];
            #pragma unroll
            for (int i = 0; i < 4; ++i) p_[i] = KPs[tq * 4 + i][kk];
            #pragma unroll
            for (int j = 0; j < 4; ++j) v_[j] = Vs[kk][tk * 4 + j];
            #pragma unroll
            for (int i = 0; i < 4; ++i)
                #pragma unroll
                for (int j = 0; j < 4; ++j)
                    O[i][j] = fmaf(p_[i], v_[j], O[i][j]);
        }
    }

    #pragma unroll
    for (int i = 0; i < 4; ++i) {
        const int t = q0 + tq * 4 + i;
        const float inv = 1.0f / l_[i];
        const size_t o = ((size_t)b * T_ + t) * C_ + h * HD_ + tk * 4;
        #pragma unroll
        for (int j = 0; j < 4; ++j) out[o + j] = O[i][j] * inv;
    }
}

// ---------------------------------------------------------------------------
// Row-wise LayerNorm over C=384.  One wave per row, 4 rows per block.
// ---------------------------------------------------------------------------
__global__ __launch_bounds__(256)
void ln_kernel(const float* __restrict__ in, const float* __restrict__ g,
               const float* __restrict__ bta, float* __restrict__ out)
{
    const int lane = threadIdx.x & 63;
    const int wv   = threadIdx.x >> 6;
    const size_t row = (size_t)blockIdx.x * 4 + wv;
    const float* x = in + row * C_;

    float vals[6];
    float s = 0.0f;
    #pragma unroll
    for (int i = 0; i < 6; ++i) { vals[i] = x[lane + i * 64]; s += vals[i]; }
    #pragma unroll
    for (int off = 1; off < 64; off <<= 1) s += __shfl_xor(s, off, 64);
    const float mean = s * (1.0f / 384.0f);

    float vs = 0.0f;
    #pragma unroll
    for (int i = 0; i < 6; ++i) { float d = vals[i] - mean; vs += d * d; }
    #pragma unroll
    for (int off = 1; off < 64; off <<= 1) vs += __shfl_xor(vs, off, 64);
    const float inv = rsqrtf(vs * (1.0f / 384.0f) + 1e-5f);

    float* y = out + row * C_;
    #pragma unroll
    for (int i = 0; i < 6; ++i) {
        int c = lane + i * 64;
        y[c] = g[c] * (vals[i] - mean) * inv + bta[c];
    }
}

// ---------------------------------------------------------------------------
extern "C" void kernel_launch(void* const* d_in, const int* in_sizes, int n_in,
                              void* d_out, int out_size, void* d_ws, size_t ws_size,
                              hipStream_t stream)
{
    const float* x    = (const float*)d_in[0];
    const float* q1w  = (const float*)d_in[1];  const float* q1b = (const float*)d_in[2];
    const float* k1w  = (const float*)d_in[3];  const float* k1b = (const float*)d_in[4];
    const float* v1w  = (const float*)d_in[5];  const float* v1b = (const float*)d_in[6];
    const float* p1w  = (const float*)d_in[7];  const float* p1b = (const float*)d_in[8];
    const float* ln1g = (const float*)d_in[9];  const float* ln1b = (const float*)d_in[10];
    const float* q2w  = (const float*)d_in[11]; const float* q2b = (const float*)d_in[12];
    const float* k2w  = (const float*)d_in[13]; const float* k2b = (const float*)d_in[14];
    const float* v2w  = (const float*)d_in[15]; const float* v2b = (const float*)d_in[16];
    const float* p2w  = (const float*)d_in[17]; const float* p2b = (const float*)d_in[18];
    const float* ln2g = (const float*)d_in[19]; const float* ln2b = (const float*)d_in[20];
    const float* f1w  = (const float*)d_in[21]; const float* f1b = (const float*)d_in[22];
    const float* f2w  = (const float*)d_in[23]; const float* f2b = (const float*)d_in[24];
    const float* ln3g = (const float*)d_in[25]; const float* ln3b = (const float*)d_in[26];

    // --- batch-chunked pipeline: attention mixes only within a batch; all
    // other ops are row-wise, so the whole 2-layer+FF network is batch-
    // separable.  Choose the largest chunk whose 5 scratch slices fit d_ws.
    int CB = 64;
    while (CB > 1 && (size_t)5 * CB * T_ * C_ * sizeof(float) > ws_size) CB >>= 1;

    const size_t chunkS = (size_t)CB * T_ * C_;   // floats per slice
    float* ws   = (float*)d_ws;
    float* q    = ws + 0 * chunkS;
    float* k    = ws + 1 * chunkS;
    float* v    = ws + 2 * chunkS;
    float* abuf = ws + 3 * chunkS;
    float* bufA = ws + 4 * chunkS;
    float* tmp  = ws;                 // FF intermediate: 4*chunkS overlays q..abuf

    const dim3 blk(256);
    const int Mc = CB * T_;           // rows per chunk

    for (int b0 = 0; b0 < B_; b0 += CB) {
        const float* xc  = x + (size_t)b0 * T_ * C_;
        float*       oc  = (float*)d_out + (size_t)b0 * T_ * C_;   // out2 lives here

        // ---- layer 1 ----
        gemm_qkv<<<dim3(Mc / 64, 3 * H_), blk, 0, stream>>>(xc, q1w, q1b, k1w, k1b, v1w, v1b, q, k, v);
        attn_kernel<<<dim3(T_ / 64, H_, CB), blk, 0, stream>>>(q, k, v, abuf);
        gemm_ep<0><<<dim3(Mc / 64, C_ / 64), blk, 0, stream>>>(abuf, p1w, p1b, xc, bufA, C_, C_);
        ln_kernel<<<dim3(Mc / 4), blk, 0, stream>>>(bufA, ln1g, ln1b, bufA);

        // ---- layer 2 ----
        gemm_qkv<<<dim3(Mc / 64, 3 * H_), blk, 0, stream>>>(bufA, q2w, q2b, k2w, k2b, v2w, v2b, q, k, v);
        attn_kernel<<<dim3(T_ / 64, H_, CB), blk, 0, stream>>>(q, k, v, abuf);
        gemm_ep<0><<<dim3(Mc / 64, C_ / 64), blk, 0, stream>>>(abuf, p2w, p2b, bufA, oc, C_, C_);
        ln_kernel<<<dim3(Mc / 4), blk, 0, stream>>>(oc, ln2g, ln2b, oc);

        // ---- feed-forward ----  (tmp overlays q,k,v,abuf — all dead now)
        gemm_ep<1><<<dim3(Mc / 64, FF_ / 64), blk, 0, stream>>>(oc, f1w, f1b, nullptr, tmp, C_, FF_);
        gemm_ep<0><<<dim3(Mc / 64, C_ / 64), blk, 0, stream>>>(tmp, f2w, f2b, oc, bufA, FF_, C_);
        ln_kernel<<<dim3(Mc / 4), blk, 0, stream>>>(bufA, ln3g, ln3b, oc);
    }
}

// Round 3
// 852.813 us; speedup vs baseline: 3.8102x; 3.8102x over previous
//
#include <hip/hip_runtime.h>
#include <cstddef>
#include <cstdint>

#define B_ 64
#define T_ 512
#define C_ 384
#define H_ 6
#define HD_ 64
#define FF_ 1536

typedef unsigned short u16;
typedef __attribute__((ext_vector_type(8))) __bf16 bf16x8;
typedef __attribute__((ext_vector_type(8))) short short8;
typedef __attribute__((ext_vector_type(4))) float f32x4;

#define MFMA_BF16(a, b, c) __builtin_amdgcn_mfma_f32_16x16x32_bf16((a), (b), (c), 0, 0, 0)

__device__ __forceinline__ u16 f2bf(float f) {
    union { float f; unsigned u; } x; x.f = f;
    unsigned r = x.u + 0x7fff + ((x.u >> 16) & 1);   // RTNE
    return (u16)(r >> 16);
}

__device__ __forceinline__ void gload16(const u16* g, u16* l) {
    __builtin_amdgcn_global_load_lds(
        (const __attribute__((address_space(1))) void*)g,
        (__attribute__((address_space(3))) void*)l, 16, 0, 0);
}

// ---------------------------------------------------------------------------
// prep: cast + transpose weights to bf16 [N][K], concat qkv biases, trig table
// blockIdx.y = job id
// ---------------------------------------------------------------------------
__global__ __launch_bounds__(256)
void prep_kernel(const float* __restrict__ q1w, const float* __restrict__ k1w, const float* __restrict__ v1w,
                 const float* __restrict__ q2w, const float* __restrict__ k2w, const float* __restrict__ v2w,
                 const float* __restrict__ p1w, const float* __restrict__ p2w,
                 const float* __restrict__ f1w, const float* __restrict__ f2w,
                 const float* __restrict__ q1b, const float* __restrict__ k1b, const float* __restrict__ v1b,
                 const float* __restrict__ q2b, const float* __restrict__ k2b, const float* __restrict__ v2b,
                 u16* wq1, u16* wq2, u16* p1t, u16* p2t, u16* f1t, u16* f2t,
                 float* bq1, float* bq2, float* cst, float* snt)
{
    const int job = blockIdx.y;
    const int idx = blockIdx.x * 256 + threadIdx.x;
    if (job <= 1) {                       // qkv weights: [n=1152][k=384], n = which*384+h*64+d
        if (idx >= 1152 * 384) return;
        const int n = idx / 384, k = idx - n * 384;
        const int which = n / 384 + 0;    // always 0.. wait n<1152
        const int w2 = n >> 7;            // unused
        (void)which; (void)w2;
        const int wsel = n / 384;         // 0,1,2
        const int rest = n - wsel * 384;
        const int h = rest >> 6, d = rest & 63;
        const float* src;
        if (job == 0) src = (wsel == 0 ? q1w : wsel == 1 ? k1w : v1w);
        else          src = (wsel == 0 ? q2w : wsel == 1 ? k2w : v2w);
        const float v = src[((size_t)h * 384 + k) * 64 + d];
        (job == 0 ? wq1 : wq2)[idx] = f2bf(v);
    } else if (job <= 3) {                // proj: [n=384][k=384] = pw[k][n]
        if (idx >= 384 * 384) return;
        const int n = idx / 384, k = idx - n * 384;
        const float* src = (job == 2 ? p1w : p2w);
        (job == 2 ? p1t : p2t)[idx] = f2bf(src[(size_t)k * 384 + n]);
    } else if (job == 4) {                // f1: [n=1536][k=384] = f1w[k][n]
        if (idx >= 1536 * 384) return;
        const int n = idx / 384, k = idx - n * 384;
        f1t[idx] = f2bf(f1w[(size_t)k * 1536 + n]);
    } else if (job == 5) {                // f2: [n=384][k=1536] = f2w[k][n]
        if (idx >= 384 * 1536) return;
        const int n = idx / 1536, k = idx - n * 1536;
        f2t[idx] = f2bf(f2w[(size_t)k * 384 + n]);
    } else {                              // biases + trig table
        if (idx < 1152) {
            const int wsel = idx / 384, r = idx - wsel * 384;
            bq1[idx] = (wsel == 0 ? q1b : wsel == 1 ? k1b : v1b)[r];
        } else if (idx < 2304) {
            const int j = idx - 1152;
            const int wsel = j / 384, r = j - wsel * 384;
            bq2[j] = (wsel == 0 ? q2b : wsel == 1 ? k2b : v2b)[r];
        } else if (idx < 2816) {
            const int t = idx - 2304; cst[t] = cosf((float)t);
        } else if (idx < 3328) {
            const int t = idx - 2816; snt[t] = sinf((float)t);
        }
    }
}

// ---------------------------------------------------------------------------
// cast fp32 -> bf16, vectorized
// ---------------------------------------------------------------------------
__global__ __launch_bounds__(256)
void cast_kernel(const float* __restrict__ in, u16* __restrict__ out, int n4)
{
    int i = blockIdx.x * 256 + threadIdx.x;
    const int stride = gridDim.x * 256;
    for (; i < n4; i += stride) {
        float4 v = *reinterpret_cast<const float4*>(&in[(size_t)i * 4]);
        ushort4 o;
        o.x = f2bf(v.x); o.y = f2bf(v.y); o.z = f2bf(v.z); o.w = f2bf(v.w);
        *reinterpret_cast<ushort4*>(&out[(size_t)i * 4]) = o;
    }
}

// ---------------------------------------------------------------------------
// bf16 MFMA GEMM, tile 128x128, BK=32, 256 thr = 4 waves (2x2), 4x4 frags/wave
// A [M][K] bf16, Bt [N][K] bf16 (pre-transposed).  Accum fp32.
// EPI 0: QKV (bias + RoPE for q,k; scatter to q/k/v [b,h,t,d] bf16)
// EPI 1: outf = acc + bias[n] + res[m][n]  (fp32)
// EPI 2: outb = relu(acc + bias[n])        (bf16)
// ---------------------------------------------------------------------------
template<int EPI>
__global__ __launch_bounds__(256)
void gemm_mfma(const u16* __restrict__ A, const u16* __restrict__ Bt, int K,
               const float* __restrict__ bias, const float* __restrict__ res,
               float* __restrict__ outf, u16* __restrict__ outb,
               u16* __restrict__ qo, u16* __restrict__ ko, u16* __restrict__ vo,
               const float* __restrict__ cst, const float* __restrict__ snt,
               int N)
{
    __shared__ u16 As[128 * 32];
    __shared__ u16 Bs[128 * 32];
    const int tid = threadIdx.x;
    const int w = tid >> 6, lane = tid & 63;
    const int m0 = blockIdx.x * 128, n0 = blockIdx.y * 128;
    const int wm = w >> 1, wn = w & 1;
    const int c = lane & 15, g = lane >> 4;

    const u16* gA = A + (size_t)(m0 + w * 16 + (lane >> 2)) * K + (lane & 3) * 8;
    const u16* gB = Bt + (size_t)(n0 + w * 16 + (lane >> 2)) * K + (lane & 3) * 8;
    u16* lA = As + w * 512;
    u16* lB = Bs + w * 512;

    f32x4 acc[4][4];
    #pragma unroll
    for (int i = 0; i < 4; ++i)
        #pragma unroll
        for (int j = 0; j < 4; ++j) acc[i][j] = (f32x4)0.0f;

    for (int k0 = 0; k0 < K; k0 += 32) {
        __syncthreads();
        gload16(gA + k0, lA);
        gload16(gA + k0 + (size_t)64 * K, lA + 64 * 32);
        gload16(gB + k0, lB);
        gload16(gB + k0 + (size_t)64 * K, lB + 64 * 32);
        __syncthreads();
        bf16x8 af[4], bf[4];
        #pragma unroll
        for (int fi = 0; fi < 4; ++fi)
            af[fi] = *(const bf16x8*)&As[(wm * 64 + fi * 16 + c) * 32 + g * 8];
        #pragma unroll
        for (int fj = 0; fj < 4; ++fj)
            bf[fj] = *(const bf16x8*)&Bs[(wn * 64 + fj * 16 + c) * 32 + g * 8];
        #pragma unroll
        for (int fi = 0; fi < 4; ++fi)
            #pragma unroll
            for (int fj = 0; fj < 4; ++fj)
                acc[fi][fj] = MFMA_BF16(af[fi], bf[fj], acc[fi][fj]);
    }

    // ---- epilogue ----
    if (EPI == 0) {
        const int which = blockIdx.y / 3;            // N=1152, 384 per which
        u16* dst = (which == 0 ? qo : which == 1 ? ko : vo);
        #pragma unroll
        for (int fi = 0; fi < 4; ++fi) {
            #pragma unroll
            for (int r = 0; r < 4; ++r) {
                const int m = m0 + wm * 64 + fi * 16 + 4 * g + r;
                const int t = m & 511, bb = m >> 9;
                const float cs = cst[t], sn = snt[t];
                #pragma unroll
                for (int fj = 0; fj < 4; ++fj) {
                    const int n = n0 + wn * 64 + fj * 16 + c;
                    float v = acc[fi][fj][r] + bias[n];
                    const float vp = __shfl_xor(v, 1);
                    float ov;
                    if (which < 2)
                        ov = ((n & 1) == 0) ? cs * v - sn * vp : sn * vp + cs * v;
                    else
                        ov = v;
                    const int rest = n - which * 384;
                    const int h = rest >> 6, d = rest & 63;
                    dst[(((size_t)bb * H_ + h) * T_ + t) * 64 + d] = f2bf(ov);
                }
            }
        }
    } else {
        #pragma unroll
        for (int fi = 0; fi < 4; ++fi) {
            #pragma unroll
            for (int r = 0; r < 4; ++r) {
                const int m = m0 + wm * 64 + fi * 16 + 4 * g + r;
                #pragma unroll
                for (int fj = 0; fj < 4; ++fj) {
                    const int n = n0 + wn * 64 + fj * 16 + c;
                    float v = acc[fi][fj][r] + bias[n];
                    if (EPI == 1) {
                        v += res[(size_t)m * N + n];
                        outf[(size_t)m * N + n] = v;
                    } else {
                        outb[(size_t)m * N + n] = f2bf(fmaxf(v, 0.0f));
                    }
                }
            }
        }
    }
}

// ---------------------------------------------------------------------------
// Flash attention, bf16 MFMA.  Block = (qtile, h, b); 4 waves x 16 q-rows.
// Q,K,V [b][h][t][64] bf16 -> out [b*t][C] bf16 at col h*64.
// ---------------------------------------------------------------------------
#define KS_B(r, chB) ((r) * 176 + (chB) * 16)
#define VT_B(d, t)   ((d) * 176 + ((((t) >> 3) ^ ((d) & 7) ^ ((d) >> 3)) << 4) + (((t) & 7) << 1))

__global__ __launch_bounds__(256)
void attn_mfma(const u16* __restrict__ Q, const u16* __restrict__ K,
               const u16* __restrict__ V, u16* __restrict__ out)
{
    __shared__ u16 Ks[64 * 88];
    __shared__ u16 Vt[64 * 88];
    __shared__ u16 Ps[4][16 * 88];

    const int qt = blockIdx.x, h = blockIdx.y, b = blockIdx.z;
    const int tid = threadIdx.x;
    const int w = tid >> 6, lane = tid & 63;
    const int c = lane & 15, g = lane >> 4;
    const size_t base = ((size_t)b * H_ + h) * T_ * 64;
    const int qrow0 = qt * 64 + w * 16;
    const float scale = 0.05103103630798288f;   // 384^-0.5

    // Q fragments (2 k-halves of HD=64), kept in registers
    bf16x8 qf[2];
    #pragma unroll
    for (int kh = 0; kh < 2; ++kh)
        qf[kh] = *(const bf16x8*)&Q[base + (size_t)(qrow0 + c) * 64 + kh * 32 + g * 8];

    f32x4 O[4];
    float m_[4], l_[4];
    #pragma unroll
    for (int i = 0; i < 4; ++i) { O[i] = (f32x4)0.0f; m_[i] = -INFINITY; l_[i] = 0.0f; }

    u16* Pw = Ps[w];

    for (int kt = 0; kt <= qt; ++kt) {
        __syncthreads();
        // stage K tile [64][64] and V^T tile (swizzled)
        #pragma unroll
        for (int s = 0; s < 2; ++s) {
            const int idx = tid + s * 256;          // 0..511
            const int r = idx >> 3, ch = idx & 7;
            const size_t gsrc = base + (size_t)(kt * 64 + r) * 64 + ch * 8;
            short8 kv = *(const short8*)&K[gsrc];
            *(short8*)((char*)Ks + KS_B(r, ch)) = kv;
            short8 vv = *(const short8*)&V[gsrc];
            #pragma unroll
            for (int j = 0; j < 8; ++j)
                *(u16*)((char*)Vt + VT_B(ch * 8 + j, r)) = (u16)vv[j];
        }
        __syncthreads();

        // S = Q K^T : 4 col-frags x 2 k-halves
        f32x4 S[4];
        #pragma unroll
        for (int fc = 0; fc < 4; ++fc) {
            S[fc] = (f32x4)0.0f;
            #pragma unroll
            for (int kh = 0; kh < 2; ++kh) {
                bf16x8 kf = *(const bf16x8*)((char*)Ks + KS_B(fc * 16 + c, kh * 4 + g));
                S[fc] = MFMA_BF16(qf[kh], kf, S[fc]);
            }
        }

        // scale + causal mask + online softmax (rows shared by 16 lanes, width-16 shuffles)
        const bool diag = (kt == qt);
        #pragma unroll
        for (int r = 0; r < 4; ++r) {
            const int qloc = w * 16 + 4 * g + r;     // q within 64-tile
            float mx = -INFINITY;
            #pragma unroll
            for (int fc = 0; fc < 4; ++fc) {
                float sv = S[fc][r] * scale;
                if (diag && (fc * 16 + c > qloc)) sv = -INFINITY;
                S[fc][r] = sv;
                mx = fmaxf(mx, sv);
            }
            #pragma unroll
            for (int off = 1; off < 16; off <<= 1)
                mx = fmaxf(mx, __shfl_xor(mx, off, 16));
            const float mnew = fmaxf(m_[r], mx);
            const float corr = __expf(m_[r] - mnew);
            m_[r] = mnew;
            float su = 0.0f;
            #pragma unroll
            for (int fc = 0; fc < 4; ++fc) {
                const float p = __expf(S[fc][r] - mnew);
                S[fc][r] = p; su += p;
            }
            #pragma unroll
            for (int off = 1; off < 16; off <<= 1)
                su += __shfl_xor(su, off, 16);
            l_[r] = l_[r] * corr + su;
            #pragma unroll
            for (int fd = 0; fd < 4; ++fd) O[fd][r] *= corr;
        }

        // P -> per-wave LDS (bf16), then PV via MFMA
        #pragma unroll
        for (int fc = 0; fc < 4; ++fc)
            #pragma unroll
            for (int r = 0; r < 4; ++r)
                *(u16*)((char*)Pw + (4 * g + r) * 176 + (fc * 16 + c) * 2) = f2bf(S[fc][r]);

        bf16x8 pa[2];
        #pragma unroll
        for (int kh = 0; kh < 2; ++kh)
            pa[kh] = *(const bf16x8*)((char*)Pw + c * 176 + kh * 64 + g * 16);
        #pragma unroll
        for (int fd = 0; fd < 4; ++fd) {
            const int d = fd * 16 + c;
            #pragma unroll
            for (int kh = 0; kh < 2; ++kh) {
                const int kb = kh * 4 + g;
                bf16x8 vf = *(const bf16x8*)((char*)Vt + d * 176 + (((kb) ^ (d & 7) ^ (d >> 3)) << 4));
                O[fd] = MFMA_BF16(pa[kh], vf, O[fd]);
            }
        }
    }

    // write O / l  ->  out[b*T + t][h*64 + d]  (bf16)
    #pragma unroll
    for (int r = 0; r < 4; ++r) {
        const int t = qrow0 + 4 * g + r;
        const float inv = 1.0f / l_[r];
        const size_t o = ((size_t)b * T_ + t) * C_ + h * 64;
        #pragma unroll
        for (int fd = 0; fd < 4; ++fd)
            out[o + fd * 16 + c] = f2bf(O[fd][r] * inv);
    }
}

// ---------------------------------------------------------------------------
// LayerNorm over C=384, fp32 in, fp32 and/or bf16 out.  1 wave/row.
// ---------------------------------------------------------------------------
__global__ __launch_bounds__(256)
void ln_kernel(const float* __restrict__ in, const float* __restrict__ gam,
               const float* __restrict__ bta, float* __restrict__ outf,
               u16* __restrict__ outb)
{
    const int lane = threadIdx.x & 63;
    const int wv   = threadIdx.x >> 6;
    const size_t row = (size_t)blockIdx.x * 4 + wv;
    const float* x = in + row * C_;

    float vals[6];
    float s = 0.0f;
    #pragma unroll
    for (int i = 0; i < 6; ++i) { vals[i] = x[lane + i * 64]; s += vals[i]; }
    #pragma unroll
    for (int off = 1; off < 64; off <<= 1) s += __shfl_xor(s, off, 64);
    const float mean = s * (1.0f / 384.0f);

    float vs = 0.0f;
    #pragma unroll
    for (int i = 0; i < 6; ++i) { const float d = vals[i] - mean; vs += d * d; }
    #pragma unroll
    for (int off = 1; off < 64; off <<= 1) vs += __shfl_xor(vs, off, 64);
    const float inv = rsqrtf(vs * (1.0f / 384.0f) + 1e-5f);

    #pragma unroll
    for (int i = 0; i < 6; ++i) {
        const int cc = lane + i * 64;
        const float y = gam[cc] * (vals[i] - mean) * inv + bta[cc];
        if (outf) outf[row * C_ + cc] = y;
        if (outb) outb[row * C_ + cc] = f2bf(y);
    }
}

// ---------------------------------------------------------------------------
extern "C" void kernel_launch(void* const* d_in, const int* in_sizes, int n_in,
                              void* d_out, int out_size, void* d_ws, size_t ws_size,
                              hipStream_t stream)
{
    const float* x    = (const float*)d_in[0];
    const float* q1w  = (const float*)d_in[1];  const float* q1b = (const float*)d_in[2];
    const float* k1w  = (const float*)d_in[3];  const float* k1b = (const float*)d_in[4];
    const float* v1w  = (const float*)d_in[5];  const float* v1b = (const float*)d_in[6];
    const float* p1w  = (const float*)d_in[7];  const float* p1b = (const float*)d_in[8];
    const float* ln1g = (const float*)d_in[9];  const float* ln1b = (const float*)d_in[10];
    const float* q2w  = (const float*)d_in[11]; const float* q2b = (const float*)d_in[12];
    const float* k2w  = (const float*)d_in[13]; const float* k2b = (const float*)d_in[14];
    const float* v2w  = (const float*)d_in[15]; const float* v2b = (const float*)d_in[16];
    const float* p2w  = (const float*)d_in[17]; const float* p2b = (const float*)d_in[18];
    const float* ln2g = (const float*)d_in[19]; const float* ln2b = (const float*)d_in[20];
    const float* f1w  = (const float*)d_in[21]; const float* f1b = (const float*)d_in[22];
    const float* f2w  = (const float*)d_in[23]; const float* f2b = (const float*)d_in[24];
    const float* ln3g = (const float*)d_in[25]; const float* ln3b = (const float*)d_in[26];

    // ---- workspace layout: bf16 weights, fp32 biases/tables, chunk slices ----
    const size_t WQKV = 1152 * 384, WP = 384 * 384, WF = 1536 * 384;
    u16* wq1 = (u16*)d_ws;
    u16* wq2 = wq1 + WQKV;
    u16* p1t = wq2 + WQKV;
    u16* p2t = p1t + WP;
    u16* f1t = p2t + WP;
    u16* f2t = f1t + WF;
    float* bq1 = (float*)(f2t + WF);
    float* bq2 = bq1 + 1152;
    float* cst = bq2 + 1152;
    float* snt = cst + 512;
    u16* chunkBase = (u16*)(snt + 512);
    const size_t fixedBytes = (size_t)((char*)chunkBase - (char*)d_ws);

    // chunk size: 6 bf16 slices + 2 fp32 slices of Mc*C each
    int CB = 64;
    while (CB > 1 && fixedBytes + 20ull * CB * T_ * C_ > ws_size) CB >>= 1;
    const size_t McC = (size_t)CB * T_ * C_;
    const int Mc = CB * T_;

    u16* sQ  = chunkBase;
    u16* sK  = sQ + McC;
    u16* sV  = sK + McC;
    u16* sAb = sV + McC;
    u16* sX  = sAb + McC;        // shared: x-cast, then out1 bf16
    u16* sO2 = sX + McC;         // out2 bf16
    u16* tmp = sQ;               // FF intermediate: 4 slices overlay q,k,v,abuf
    float* bufF  = (float*)(sO2 + McC);
    float* out1f = bufF + McC;

    const dim3 blk(256);

    // weights prep (once per call)
    prep_kernel<<<dim3(2304, 7), blk, 0, stream>>>(
        q1w, k1w, v1w, q2w, k2w, v2w, p1w, p2w, f1w, f2w,
        q1b, k1b, v1b, q2b, k2b, v2b,
        wq1, wq2, p1t, p2t, f1t, f2t, bq1, bq2, cst, snt);

    for (int b0 = 0; b0 < B_; b0 += CB) {
        const float* xc = x + (size_t)b0 * T_ * C_;
        float*       oc = (float*)d_out + (size_t)b0 * T_ * C_;

        cast_kernel<<<dim3(2048), blk, 0, stream>>>(xc, sX, (int)(McC / 4));

        // ---- layer 1 ----
        gemm_mfma<0><<<dim3(Mc / 128, 9), blk, 0, stream>>>(sX, wq1, 384, bq1,
            nullptr, nullptr, nullptr, sQ, sK, sV, cst, snt, 1152);
        attn_mfma<<<dim3(T_ / 64, H_, CB), blk, 0, stream>>>(sQ, sK, sV, sAb);
        gemm_mfma<1><<<dim3(Mc / 128, 3), blk, 0, stream>>>(sAb, p1t, 384, p1b,
            xc, bufF, nullptr, nullptr, nullptr, nullptr, cst, snt, 384);
        ln_kernel<<<dim3(Mc / 4), blk, 0, stream>>>(bufF, ln1g, ln1b, out1f, sX);

        // ---- layer 2 ----
        gemm_mfma<0><<<dim3(Mc / 128, 9), blk, 0, stream>>>(sX, wq2, 384, bq2,
            nullptr, nullptr, nullptr, sQ, sK, sV, cst, snt, 1152);
        attn_mfma<<<dim3(T_ / 64, H_, CB), blk, 0, stream>>>(sQ, sK, sV, sAb);
        gemm_mfma<1><<<dim3(Mc / 128, 3), blk, 0, stream>>>(sAb, p2t, 384, p2b,
            out1f, bufF, nullptr, nullptr, nullptr, nullptr, cst, snt, 384);
        ln_kernel<<<dim3(Mc / 4), blk, 0, stream>>>(bufF, ln2g, ln2b, oc, sO2);

        // ---- feed-forward ----
        gemm_mfma<2><<<dim3(Mc / 128, 12), blk, 0, stream>>>(sO2, f1t, 384, f1b,
            nullptr, nullptr, tmp, nullptr, nullptr, nullptr, cst, snt, 1536);
        gemm_mfma<1><<<dim3(Mc / 128, 3), blk, 0, stream>>>(tmp, f2t, 1536, f2b,
            oc, bufF, nullptr, nullptr, nullptr, nullptr, cst, snt, 384);
        ln_kernel<<<dim3(Mc / 4), blk, 0, stream>>>(bufF, ln3g, ln3b, oc, nullptr);
    }
}